// Round 1
// baseline (1244.889 us; speedup 1.0000x reference)
//
#include <hip/hip_runtime.h>

// Problem constants (fixed by setup_inputs).
constexpr int BATCH = 2;
constexpr int NSEQ  = 2048;
constexpr int DIM   = 1024;
constexpr int NH    = 16;
constexpr int DH    = 64;
constexpr int MROWS = BATCH * NSEQ;       // 4096
constexpr float ATTN_SCALE = 8.0f;        // sqrt(DH): reference MULTIPLIES by sqrt(d)

// ---------------------------------------------------------------------------
// fp32 SGEMM: C[M,N] = A[M,K] @ Bmat[K,N], all row-major.
// 128x128 block tile, BK=16, 256 threads, 8x8 micro-tile.
// M,N multiples of 128; K multiple of 16 (true for all three calls).
// ---------------------------------------------------------------------------
constexpr int BM = 128, BN = 128, BK = 16;

__global__ __launch_bounds__(256, 2) void sgemm128(
    const float* __restrict__ A, const float* __restrict__ Bmat,
    float* __restrict__ C, int M, int N, int K) {
  __shared__ float As[BK][BM + 4];   // +4 pad: store conflicts -> 2-way (free)
  __shared__ float Bs[BK][BN + 4];

  const int tid = threadIdx.x;
  const int bm = blockIdx.y * BM;
  const int bn = blockIdx.x * BN;

  // A-tile loads: 128 rows x 16 cols = 512 float4; 2 per thread.
  const int ar = tid >> 2;            // 0..63
  const int ac = (tid & 3) << 2;      // 0,4,8,12
  // B-tile loads: 16 rows x 128 cols = 512 float4; 2 per thread.
  const int br = tid >> 5;            // 0..7
  const int bc = (tid & 31) << 2;     // 0..124
  // micro-tile position
  const int tr = (tid >> 4) << 3;     // 0..120
  const int tc = (tid & 15) << 3;     // 0..120

  float acc[8][8];
#pragma unroll
  for (int i = 0; i < 8; ++i)
#pragma unroll
    for (int j = 0; j < 8; ++j) acc[i][j] = 0.0f;

  const float* Ap  = A + (size_t)(bm + ar) * K + ac;
  const float* Ap2 = Ap + (size_t)64 * K;
  const float* Bp  = Bmat + (size_t)br * N + bn + bc;
  const float* Bp2 = Bp + (size_t)8 * N;

  for (int k0 = 0; k0 < K; k0 += BK) {
    float4 a0 = *(const float4*)(Ap + k0);
    float4 a1 = *(const float4*)(Ap2 + k0);
    float4 b0 = *(const float4*)(Bp + (size_t)k0 * N);
    float4 b1 = *(const float4*)(Bp2 + (size_t)k0 * N);
    __syncthreads();   // previous iteration's compute done before overwrite
    As[ac + 0][ar] = a0.x; As[ac + 1][ar] = a0.y;
    As[ac + 2][ar] = a0.z; As[ac + 3][ar] = a0.w;
    As[ac + 0][64 + ar] = a1.x; As[ac + 1][64 + ar] = a1.y;
    As[ac + 2][64 + ar] = a1.z; As[ac + 3][64 + ar] = a1.w;
    *(float4*)&Bs[br][bc]     = b0;
    *(float4*)&Bs[br + 8][bc] = b1;
    __syncthreads();
#pragma unroll
    for (int k = 0; k < BK; ++k) {
      float av[8], bv[8];
      *(float4*)&av[0] = *(const float4*)&As[k][tr];
      *(float4*)&av[4] = *(const float4*)&As[k][tr + 4];
      *(float4*)&bv[0] = *(const float4*)&Bs[k][tc];
      *(float4*)&bv[4] = *(const float4*)&Bs[k][tc + 4];
#pragma unroll
      for (int i = 0; i < 8; ++i)
#pragma unroll
        for (int j = 0; j < 8; ++j)
          acc[i][j] = fmaf(av[i], bv[j], acc[i][j]);
    }
  }

#pragma unroll
  for (int i = 0; i < 8; ++i) {
    float* Cp = C + (size_t)(bm + tr + i) * N + bn + tc;
    float4 c0 = {acc[i][0], acc[i][1], acc[i][2], acc[i][3]};
    float4 c1 = {acc[i][4], acc[i][5], acc[i][6], acc[i][7]};
    *(float4*)(Cp)     = c0;
    *(float4*)(Cp + 4) = c1;
  }
}

// ---------------------------------------------------------------------------
// Flash attention, fp32. One block = one (batch, head, 64-query tile).
// qbuf: [B][NSEQ][DIM]  (q at col head*64)
// kvbuf:[B][NSEQ][2*DIM] (k at col head*64, v at col DIM + head*64)
// ho:   [B][NSEQ][DIM]  head-concatenated attention output
// ---------------------------------------------------------------------------
constexpr int TI = 64;   // query tile
constexpr int TJ = 64;   // key tile

__global__ __launch_bounds__(256, 2) void attn64(
    const float* __restrict__ qbuf,
    const float* __restrict__ kvbuf,
    float* __restrict__ ho) {
  __shared__ float Qs[TI][DH + 1];   // stride 65 -> hot reads are <=2-way (free)
  __shared__ float Ks[TJ][DH + 1];
  __shared__ float Vs[TJ][DH + 1];
  __shared__ float Ss[TI][TJ + 1];
  __shared__ float red[TI][4];
  __shared__ float mrow[TI], lrow[TI], arow[TI];

  const int tid = threadIdx.x;
  const int i0 = blockIdx.x * TI;
  const int bh = blockIdx.y;
  const int batch = bh >> 4;
  const int head = bh & 15;

  // tile-load mapping: 4 threads per row, 16 consecutive floats each (4 x float4)
  const int lr = tid >> 2;            // 0..63
  const int lc = (tid & 3) << 2;      // 0,4,8,12

  const float* qb = qbuf + (size_t)batch * NSEQ * DIM + (size_t)head * DH;
  const float* kb = kvbuf + (size_t)batch * NSEQ * (2 * DIM) + (size_t)head * DH;
  const float* vb = kb + DIM;

  // load + scale Q tile
#pragma unroll
  for (int j = 0; j < 4; ++j) {
    float4 t = *(const float4*)(qb + (size_t)(i0 + lr) * DIM + lc + j * 16);
    Qs[lr][lc + j * 16 + 0] = t.x * ATTN_SCALE;
    Qs[lr][lc + j * 16 + 1] = t.y * ATTN_SCALE;
    Qs[lr][lc + j * 16 + 2] = t.z * ATTN_SCALE;
    Qs[lr][lc + j * 16 + 3] = t.w * ATTN_SCALE;
  }
  if (tid < TI) { mrow[tid] = -1e30f; lrow[tid] = 0.0f; }

  // compute mapping: 4x4 micro-tile for both QK^T and PV
  const int ti = (tid >> 4) << 2;     // 0..60 (rows)
  const int tj = (tid & 15) << 2;     // 0..60 (cols / v-dims)
  float Ot[4][4];
#pragma unroll
  for (int i = 0; i < 4; ++i)
#pragma unroll
    for (int j = 0; j < 4; ++j) Ot[i][j] = 0.0f;

  __syncthreads();

  for (int j0 = 0; j0 < NSEQ; j0 += TJ) {
    // stage K, V tiles
#pragma unroll
    for (int j = 0; j < 4; ++j) {
      float4 t = *(const float4*)(kb + (size_t)(j0 + lr) * (2 * DIM) + lc + j * 16);
      Ks[lr][lc + j * 16 + 0] = t.x;
      Ks[lr][lc + j * 16 + 1] = t.y;
      Ks[lr][lc + j * 16 + 2] = t.z;
      Ks[lr][lc + j * 16 + 3] = t.w;
      float4 u = *(const float4*)(vb + (size_t)(j0 + lr) * (2 * DIM) + lc + j * 16);
      Vs[lr][lc + j * 16 + 0] = u.x;
      Vs[lr][lc + j * 16 + 1] = u.y;
      Vs[lr][lc + j * 16 + 2] = u.z;
      Vs[lr][lc + j * 16 + 3] = u.w;
    }
    __syncthreads();

    // S = (scaled Q) K^T, 4x4 per thread
    float s[4][4];
#pragma unroll
    for (int i = 0; i < 4; ++i)
#pragma unroll
      for (int j = 0; j < 4; ++j) s[i][j] = 0.0f;
#pragma unroll
    for (int k = 0; k < DH; ++k) {
      float qv[4], kv4[4];
#pragma unroll
      for (int i = 0; i < 4; ++i) qv[i] = Qs[ti + i][k];
#pragma unroll
      for (int j = 0; j < 4; ++j) kv4[j] = Ks[tj + j][k];
#pragma unroll
      for (int i = 0; i < 4; ++i)
#pragma unroll
        for (int j = 0; j < 4; ++j)
          s[i][j] = fmaf(qv[i], kv4[j], s[i][j]);
    }
#pragma unroll
    for (int i = 0; i < 4; ++i)
#pragma unroll
      for (int j = 0; j < 4; ++j) Ss[ti + i][tj + j] = s[i][j];
    __syncthreads();

    // row stats: 4 threads per row, 16 cols each
    const int r = tid >> 2;
    const int qd = (tid & 3) << 4;
    float lm = -1e30f;
#pragma unroll
    for (int c = 0; c < 16; ++c) lm = fmaxf(lm, Ss[r][qd + c]);
    red[r][tid & 3] = lm;
    __syncthreads();
    if (tid < TI) {
      float mo = mrow[tid];
      float mn = fmaxf(fmaxf(red[tid][0], red[tid][1]),
                       fmaxf(red[tid][2], red[tid][3]));
      mn = fmaxf(mo, mn);
      mrow[tid] = mn;
      arow[tid] = __expf(mo - mn);
    }
    __syncthreads();

    // P = exp(S - m), row partial sums
    float ls = 0.0f;
    const float mr = mrow[r];
#pragma unroll
    for (int c = 0; c < 16; ++c) {
      float p = __expf(Ss[r][qd + c] - mr);
      Ss[r][qd + c] = p;
      ls += p;
    }
    red[r][tid & 3] = ls;
    __syncthreads();
    if (tid < TI)
      lrow[tid] = lrow[tid] * arow[tid] +
                  red[tid][0] + red[tid][1] + red[tid][2] + red[tid][3];

    // O = alpha*O + P V, 4x4 per thread
#pragma unroll
    for (int i = 0; i < 4; ++i) {
      float al = arow[ti + i];
#pragma unroll
      for (int j = 0; j < 4; ++j) Ot[i][j] *= al;
    }
#pragma unroll
    for (int j = 0; j < TJ; ++j) {
      float pv[4], vv[4];
#pragma unroll
      for (int i = 0; i < 4; ++i) pv[i] = Ss[ti + i][j];
#pragma unroll
      for (int jj = 0; jj < 4; ++jj) vv[jj] = Vs[j][tj + jj];
#pragma unroll
      for (int i = 0; i < 4; ++i)
#pragma unroll
        for (int jj = 0; jj < 4; ++jj)
          Ot[i][jj] = fmaf(pv[i], vv[jj], Ot[i][jj]);
    }
    __syncthreads();   // guard K/V/S overwrite in next iteration
  }

  // write head output, normalized
  float* hob = ho + (size_t)batch * NSEQ * DIM + (size_t)head * DH;
#pragma unroll
  for (int i = 0; i < 4; ++i) {
    float inv = 1.0f / lrow[ti + i];
    float4 o = {Ot[i][0] * inv, Ot[i][1] * inv, Ot[i][2] * inv, Ot[i][3] * inv};
    *(float4*)(hob + (size_t)(i0 + ti + i) * DIM + tj) = o;
  }
}

// ---------------------------------------------------------------------------
extern "C" void kernel_launch(void* const* d_in, const int* in_sizes, int n_in,
                              void* d_out, int out_size, void* d_ws, size_t ws_size,
                              hipStream_t stream) {
  const float* x     = (const float*)d_in[0];   // [B][NSEQ][DIM]
  const float* w_q   = (const float*)d_in[1];   // [DIM][DIM]
  const float* w_vk  = (const float*)d_in[2];   // [DIM][2*DIM] (k cols first, then v)
  const float* w_out = (const float*)d_in[3];   // [DIM][DIM]
  float* out = (float*)d_out;                   // [B][NSEQ][DIM]

  // workspace: q (16MB) | kv (32MB) | head-out (16MB)
  float* qbuf  = (float*)d_ws;
  float* kvbuf = qbuf + (size_t)MROWS * DIM;
  float* hobuf = kvbuf + (size_t)MROWS * 2 * DIM;

  dim3 blk(256);
  sgemm128<<<dim3(DIM / BN, MROWS / BM), blk, 0, stream>>>(
      x, w_q, qbuf, MROWS, DIM, DIM);
  sgemm128<<<dim3((2 * DIM) / BN, MROWS / BM), blk, 0, stream>>>(
      x, w_vk, kvbuf, MROWS, 2 * DIM, DIM);
  attn64<<<dim3(NSEQ / TI, BATCH * NH), blk, 0, stream>>>(qbuf, kvbuf, hobuf);
  sgemm128<<<dim3(DIM / BN, MROWS / BM), blk, 0, stream>>>(
      hobuf, w_out, out, MROWS, DIM, DIM);
}

// Round 2
// 353.494 us; speedup vs baseline: 3.5217x; 3.5217x over previous
//
#include <hip/hip_runtime.h>

typedef __bf16 bf16x8 __attribute__((ext_vector_type(8)));
typedef __bf16 bf16x4 __attribute__((ext_vector_type(4)));
typedef float f32x4 __attribute__((ext_vector_type(4)));

#define MFMA(a, b, c) __builtin_amdgcn_mfma_f32_16x16x32_bf16(a, b, c, 0, 0, 0)

constexpr int NSEQ = 2048, DIM = 1024, DH = 64;

__device__ __forceinline__ void split_bf16(float x, __bf16& h, __bf16& l) {
  h = (__bf16)x;
  l = (__bf16)(x - (float)h);
}

// ---------------------------------------------------------------------------
// W[K][N] f32  ->  WTh/WTl [N][K] bf16 (hi + residual-lo), 64x64 tiles.
// ---------------------------------------------------------------------------
__global__ __launch_bounds__(256) void transpose_split(
    const float* __restrict__ W, __bf16* __restrict__ WTh,
    __bf16* __restrict__ WTl, int N, int K) {
  __shared__ float T[64][65];
  const int t = threadIdx.x;
  const int n0 = blockIdx.x * 64, k0 = blockIdx.y * 64;
  {
    const int r = t >> 2, c4 = (t & 3) * 16;
    const float* src = W + (size_t)(k0 + r) * N + n0 + c4;
    float4 v0 = ((const float4*)src)[0];
    float4 v1 = ((const float4*)src)[1];
    float4 v2 = ((const float4*)src)[2];
    float4 v3 = ((const float4*)src)[3];
    *(float4*)&T[r][c4 + 0]  = v0;
    *(float4*)&T[r][c4 + 4]  = v1;
    *(float4*)&T[r][c4 + 8]  = v2;
    *(float4*)&T[r][c4 + 12] = v3;
  }
  __syncthreads();
  const int rn = t >> 2, kc = (t & 3) * 16;
  bf16x8 hv[2], lv[2];
#pragma unroll
  for (int half = 0; half < 2; ++half)
#pragma unroll
    for (int j = 0; j < 8; ++j) {
      float x = T[kc + half * 8 + j][rn];
      __bf16 h, l;
      split_bf16(x, h, l);
      hv[half][j] = h;
      lv[half][j] = l;
    }
  __bf16* dh = WTh + (size_t)(n0 + rn) * K + k0 + kc;
  __bf16* dl = WTl + (size_t)(n0 + rn) * K + k0 + kc;
  *(bf16x8*)(dh) = hv[0]; *(bf16x8*)(dh + 8) = hv[1];
  *(bf16x8*)(dl) = lv[0]; *(bf16x8*)(dl + 8) = lv[1];
}

// ---------------------------------------------------------------------------
// Split-3 MFMA GEMM: C = A(f32, split on the fly) @ BT^T, hi/lo 3-product.
// A [4096][1024] f32, BT[h,l] [N][1024] bf16, writes Ch/Cl [4096][N] bf16
// (value scaled). 128x128 tile, BK=32, 4 waves of 4x4 16x16 fragments.
// ---------------------------------------------------------------------------
__global__ __launch_bounds__(256) void gemm_split3(
    const float* __restrict__ A, const __bf16* __restrict__ BTh,
    const __bf16* __restrict__ BTl, __bf16* __restrict__ Ch,
    __bf16* __restrict__ Cl, int N, float scale) {
  constexpr int K = 1024, GP = 40;  // pitch 40 -> 2-way LDS conflicts (free)
  __shared__ __bf16 Ash[128][GP], Asl[128][GP], Bsh[128][GP], Bsl[128][GP];
  const int t = threadIdx.x;
  const int lane = t & 63, wave = t >> 6, quad = lane >> 4, lq = lane & 15;
  const int bm = blockIdx.y * 128, bn = blockIdx.x * 128;
  const int wm = (wave >> 1) * 64, wn = (wave & 1) * 64;

  const int am = t >> 1, ak = (t & 1) * 16;  // staging: row am, 16 k-elems
  const float* Ag = A + (size_t)(bm + am) * K + ak;
  const __bf16* Bgh = BTh + (size_t)(bn + am) * K + ak;
  const __bf16* Bgl = BTl + (size_t)(bn + am) * K + ak;

  f32x4 acc[4][4];
#pragma unroll
  for (int i = 0; i < 4; ++i)
#pragma unroll
    for (int j = 0; j < 4; ++j) acc[i][j] = (f32x4){0.f, 0.f, 0.f, 0.f};

  float4 ar[4]; bf16x8 brh[2], brl[2];
  ar[0] = ((const float4*)Ag)[0]; ar[1] = ((const float4*)Ag)[1];
  ar[2] = ((const float4*)Ag)[2]; ar[3] = ((const float4*)Ag)[3];
  brh[0] = ((const bf16x8*)Bgh)[0]; brh[1] = ((const bf16x8*)Bgh)[1];
  brl[0] = ((const bf16x8*)Bgl)[0]; brl[1] = ((const bf16x8*)Bgl)[1];

  for (int k0 = 0; k0 < K; k0 += 32) {
    __syncthreads();
    {
      const float* af = (const float*)ar;
      bf16x8 h0, h1, l0, l1;
#pragma unroll
      for (int j = 0; j < 8; ++j) {
        __bf16 h, l; split_bf16(af[j], h, l); h0[j] = h; l0[j] = l;
      }
#pragma unroll
      for (int j = 0; j < 8; ++j) {
        __bf16 h, l; split_bf16(af[8 + j], h, l); h1[j] = h; l1[j] = l;
      }
      *(bf16x8*)&Ash[am][ak] = h0; *(bf16x8*)&Ash[am][ak + 8] = h1;
      *(bf16x8*)&Asl[am][ak] = l0; *(bf16x8*)&Asl[am][ak + 8] = l1;
      *(bf16x8*)&Bsh[am][ak] = brh[0]; *(bf16x8*)&Bsh[am][ak + 8] = brh[1];
      *(bf16x8*)&Bsl[am][ak] = brl[0]; *(bf16x8*)&Bsl[am][ak + 8] = brl[1];
    }
    __syncthreads();
    if (k0 + 32 < K) {  // prefetch next K-slab into registers
      const float* Ag2 = Ag + k0 + 32;
      ar[0] = ((const float4*)Ag2)[0]; ar[1] = ((const float4*)Ag2)[1];
      ar[2] = ((const float4*)Ag2)[2]; ar[3] = ((const float4*)Ag2)[3];
      const __bf16* B2h = Bgh + k0 + 32;
      const __bf16* B2l = Bgl + k0 + 32;
      brh[0] = ((const bf16x8*)B2h)[0]; brh[1] = ((const bf16x8*)B2h)[1];
      brl[0] = ((const bf16x8*)B2l)[0]; brl[1] = ((const bf16x8*)B2l)[1];
    }
    bf16x8 ah[4], al[4];
#pragma unroll
    for (int i = 0; i < 4; ++i) {
      ah[i] = *(const bf16x8*)&Ash[wm + i * 16 + lq][quad * 8];
      al[i] = *(const bf16x8*)&Asl[wm + i * 16 + lq][quad * 8];
    }
#pragma unroll
    for (int j = 0; j < 4; ++j) {
      bf16x8 bh = *(const bf16x8*)&Bsh[wn + j * 16 + lq][quad * 8];
      bf16x8 bl = *(const bf16x8*)&Bsl[wn + j * 16 + lq][quad * 8];
#pragma unroll
      for (int i = 0; i < 4; ++i) {
        acc[i][j] = MFMA(ah[i], bh, acc[i][j]);
        acc[i][j] = MFMA(al[i], bh, acc[i][j]);
        acc[i][j] = MFMA(ah[i], bl, acc[i][j]);
      }
    }
  }
#pragma unroll
  for (int i = 0; i < 4; ++i)
#pragma unroll
    for (int j = 0; j < 4; ++j) {
      const int col = bn + wn + j * 16 + lq;
#pragma unroll
      for (int r = 0; r < 4; ++r) {
        const int row = bm + wm + i * 16 + quad * 4 + r;
        float y = acc[i][j][r] * scale;
        __bf16 h, l;
        split_bf16(y, h, l);
        Ch[(size_t)row * N + col] = h;
        Cl[(size_t)row * N + col] = l;
      }
    }
}

// ---------------------------------------------------------------------------
// Plain MFMA GEMM. WHICH=0: A f32 (hi-only cast), epilogue -> vT bf16
// [b][h][d][n] (transposed per head). WHICH=1: A bf16, epilogue -> f32 C.
// ---------------------------------------------------------------------------
template <int WHICH>
__global__ __launch_bounds__(256) void gemm_plain(
    const void* __restrict__ Av, const __bf16* __restrict__ BTh,
    void* __restrict__ Cv, int N) {
  constexpr int K = 1024, GP = 40;
  __shared__ __bf16 Ash[128][GP], Bsh[128][GP];
  const int t = threadIdx.x;
  const int lane = t & 63, wave = t >> 6, quad = lane >> 4, lq = lane & 15;
  const int bm = blockIdx.y * 128, bn = blockIdx.x * 128;
  const int wm = (wave >> 1) * 64, wn = (wave & 1) * 64;
  const int am = t >> 1, ak = (t & 1) * 16;

  const float* Agf = (const float*)Av;
  const __bf16* Agb = (const __bf16*)Av;
  const float* Ag32 = Agf + (size_t)(bm + am) * K + ak;
  const __bf16* Ag16 = Agb + (size_t)(bm + am) * K + ak;
  const __bf16* Bg = BTh + (size_t)(bn + am) * K + ak;

  f32x4 acc[4][4];
#pragma unroll
  for (int i = 0; i < 4; ++i)
#pragma unroll
    for (int j = 0; j < 4; ++j) acc[i][j] = (f32x4){0.f, 0.f, 0.f, 0.f};

  float4 arf[4]; bf16x8 arb[2], br[2];
  if (WHICH == 0) {
    arf[0] = ((const float4*)Ag32)[0]; arf[1] = ((const float4*)Ag32)[1];
    arf[2] = ((const float4*)Ag32)[2]; arf[3] = ((const float4*)Ag32)[3];
  } else {
    arb[0] = ((const bf16x8*)Ag16)[0]; arb[1] = ((const bf16x8*)Ag16)[1];
  }
  br[0] = ((const bf16x8*)Bg)[0]; br[1] = ((const bf16x8*)Bg)[1];

  for (int k0 = 0; k0 < K; k0 += 32) {
    __syncthreads();
    if (WHICH == 0) {
      const float* af = (const float*)arf;
      bf16x8 h0, h1;
#pragma unroll
      for (int j = 0; j < 8; ++j) h0[j] = (__bf16)af[j];
#pragma unroll
      for (int j = 0; j < 8; ++j) h1[j] = (__bf16)af[8 + j];
      *(bf16x8*)&Ash[am][ak] = h0; *(bf16x8*)&Ash[am][ak + 8] = h1;
    } else {
      *(bf16x8*)&Ash[am][ak] = arb[0]; *(bf16x8*)&Ash[am][ak + 8] = arb[1];
    }
    *(bf16x8*)&Bsh[am][ak] = br[0]; *(bf16x8*)&Bsh[am][ak + 8] = br[1];
    __syncthreads();
    if (k0 + 32 < K) {
      if (WHICH == 0) {
        const float* A2 = Ag32 + k0 + 32;
        arf[0] = ((const float4*)A2)[0]; arf[1] = ((const float4*)A2)[1];
        arf[2] = ((const float4*)A2)[2]; arf[3] = ((const float4*)A2)[3];
      } else {
        const __bf16* A2 = Ag16 + k0 + 32;
        arb[0] = ((const bf16x8*)A2)[0]; arb[1] = ((const bf16x8*)A2)[1];
      }
      const __bf16* B2 = Bg + k0 + 32;
      br[0] = ((const bf16x8*)B2)[0]; br[1] = ((const bf16x8*)B2)[1];
    }
    bf16x8 ah[4];
#pragma unroll
    for (int i = 0; i < 4; ++i)
      ah[i] = *(const bf16x8*)&Ash[wm + i * 16 + lq][quad * 8];
#pragma unroll
    for (int j = 0; j < 4; ++j) {
      bf16x8 bh = *(const bf16x8*)&Bsh[wn + j * 16 + lq][quad * 8];
#pragma unroll
      for (int i = 0; i < 4; ++i) acc[i][j] = MFMA(ah[i], bh, acc[i][j]);
    }
  }

  if (WHICH == 0) {
    // scatter into vT[b][h][d][n]: 4 consecutive tokens -> one 8B store
    __bf16* vT = (__bf16*)Cv;
#pragma unroll
    for (int i = 0; i < 4; ++i)
#pragma unroll
      for (int j = 0; j < 4; ++j) {
        const int col = bn + wn + j * 16 + lq;       // h*64 + d
        const int row0 = bm + wm + i * 16 + quad * 4; // token index
        const int b = row0 >> 11, iseq = row0 & 2047;
        const int h = col >> 6, d = col & 63;
        bf16x4 o;
#pragma unroll
        for (int r = 0; r < 4; ++r) o[r] = (__bf16)acc[i][j][r];
        *(bf16x4*)(vT + ((size_t)(b * 16 + h) * 64 + d) * 2048 + iseq) = o;
      }
  } else {
    float* C = (float*)Cv;
#pragma unroll
    for (int i = 0; i < 4; ++i)
#pragma unroll
      for (int j = 0; j < 4; ++j) {
        const int col = bn + wn + j * 16 + lq;
#pragma unroll
        for (int r = 0; r < 4; ++r) {
          const int row = bm + wm + i * 16 + quad * 4 + r;
          C[(size_t)row * N + col] = acc[i][j][r];
        }
      }
  }
}

// ---------------------------------------------------------------------------
// MFMA flash attention. Block = (b, h, 64 q-rows); wave owns 16 q-rows.
// qh/ql, kh/kl: [4096][1024] bf16 hi/lo (q pre-scaled by 8). vT:
// [b][h][64][2048] bf16. ho: [4096][1024] bf16.
// ---------------------------------------------------------------------------
__global__ __launch_bounds__(256) void attn_mfma(
    const __bf16* __restrict__ qh, const __bf16* __restrict__ ql,
    const __bf16* __restrict__ kh, const __bf16* __restrict__ kl,
    const __bf16* __restrict__ vT, __bf16* __restrict__ ho) {
  constexpr int QP = 72;  // pitch: 2-way bank conflicts only (free)
  __shared__ __bf16 Kh[64][QP], Kl[64][QP], Vt[64][QP];
  __shared__ __bf16 Ps[4][16][QP];
  const int t = threadIdx.x;
  const int lane = t & 63, wave = t >> 6, quad = lane >> 4, lq = lane & 15;
  const int i0 = blockIdx.x * 64;
  const int bh = blockIdx.y;  // b*16 + h
  const int b = bh >> 4, head = bh & 15;
  const size_t rowbase = (size_t)b * NSEQ;

  // Q fragments pinned in registers (A-layout: m=lq, k=quad*8+jj)
  const __bf16* qph = qh + (rowbase + i0 + wave * 16 + lq) * DIM + head * DH + quad * 8;
  const __bf16* qpl = ql + (rowbase + i0 + wave * 16 + lq) * DIM + head * DH + quad * 8;
  bf16x8 qa_h[2] = {*(const bf16x8*)qph, *(const bf16x8*)(qph + 32)};
  bf16x8 qa_l[2] = {*(const bf16x8*)qpl, *(const bf16x8*)(qpl + 32)};

  f32x4 o[4];
#pragma unroll
  for (int dt = 0; dt < 4; ++dt) o[dt] = (f32x4){0.f, 0.f, 0.f, 0.f};
  float mrun[4] = {-1e30f, -1e30f, -1e30f, -1e30f};
  float lrun[4] = {0.f, 0.f, 0.f, 0.f};

  // staging: thread -> (row, 16 elems)
  const int srow = t >> 2, spart = (t & 3) * 16;
  bf16x8 r0, r1, r2, r3, r4, r5;
  auto preload = [&](int j0n) {
    const __bf16* a = kh + (rowbase + j0n + srow) * DIM + head * DH + spart;
    r0 = ((const bf16x8*)a)[0]; r1 = ((const bf16x8*)a)[1];
    const __bf16* c = kl + (rowbase + j0n + srow) * DIM + head * DH + spart;
    r2 = ((const bf16x8*)c)[0]; r3 = ((const bf16x8*)c)[1];
    const __bf16* v = vT + ((size_t)bh * 64 + srow) * NSEQ + j0n + spart;
    r4 = ((const bf16x8*)v)[0]; r5 = ((const bf16x8*)v)[1];
  };
  preload(0);

  for (int j0 = 0; j0 < NSEQ; j0 += 64) {
    __syncthreads();  // prior tile's PV reads complete
    *(bf16x8*)&Kh[srow][spart] = r0; *(bf16x8*)&Kh[srow][spart + 8] = r1;
    *(bf16x8*)&Kl[srow][spart] = r2; *(bf16x8*)&Kl[srow][spart + 8] = r3;
    *(bf16x8*)&Vt[srow][spart] = r4; *(bf16x8*)&Vt[srow][spart + 8] = r5;
    __syncthreads();
    if (j0 + 64 < NSEQ) preload(j0 + 64);

    // S = (8q)·K^T  via hi/lo 3-product
    f32x4 sf[4];
#pragma unroll
    for (int nt = 0; nt < 4; ++nt) {
      const __bf16* kr0 = &Kh[nt * 16 + lq][quad * 8];
      const __bf16* kr1 = &Kl[nt * 16 + lq][quad * 8];
      bf16x8 bh0 = *(const bf16x8*)kr0, bh1 = *(const bf16x8*)(kr0 + 32);
      bf16x8 bl0 = *(const bf16x8*)kr1, bl1 = *(const bf16x8*)(kr1 + 32);
      f32x4 s = (f32x4){0.f, 0.f, 0.f, 0.f};
      s = MFMA(qa_h[0], bh0, s); s = MFMA(qa_h[1], bh1, s);
      s = MFMA(qa_l[0], bh0, s); s = MFMA(qa_l[1], bh1, s);
      s = MFMA(qa_h[0], bl0, s); s = MFMA(qa_h[1], bl1, s);
      sf[nt] = s;
    }
    // online softmax (rows live in 16-lane groups: shfl_xor 1,2,4,8)
    float alpha4[4];
#pragma unroll
    for (int r = 0; r < 4; ++r) {
      float mx = fmaxf(fmaxf(sf[0][r], sf[1][r]), fmaxf(sf[2][r], sf[3][r]));
      mx = fmaxf(mx, __shfl_xor(mx, 1));
      mx = fmaxf(mx, __shfl_xor(mx, 2));
      mx = fmaxf(mx, __shfl_xor(mx, 4));
      mx = fmaxf(mx, __shfl_xor(mx, 8));
      float mn = fmaxf(mrun[r], mx);
      alpha4[r] = __expf(mrun[r] - mn);
      mrun[r] = mn;
    }
    float rs[4] = {0.f, 0.f, 0.f, 0.f};
#pragma unroll
    for (int nt = 0; nt < 4; ++nt)
#pragma unroll
      for (int r = 0; r < 4; ++r) {
        float p = __expf(sf[nt][r] - mrun[r]);
        rs[r] += p;
        Ps[wave][quad * 4 + r][nt * 16 + lq] = (__bf16)p;
      }
#pragma unroll
    for (int r = 0; r < 4; ++r) {
      float s = rs[r];
      s += __shfl_xor(s, 1); s += __shfl_xor(s, 2);
      s += __shfl_xor(s, 4); s += __shfl_xor(s, 8);
      lrun[r] = lrun[r] * alpha4[r] + s;
      o[0][r] *= alpha4[r]; o[1][r] *= alpha4[r];
      o[2][r] *= alpha4[r]; o[3][r] *= alpha4[r];
    }
    // wave-local LDS round trip (C-layout -> A-layout); no barrier needed,
    // but force waitcnt + ordering:
    asm volatile("s_waitcnt lgkmcnt(0)" ::: "memory");
    bf16x8 pa0 = *(const bf16x8*)&Ps[wave][lq][quad * 8];
    bf16x8 pa1 = *(const bf16x8*)&Ps[wave][lq][32 + quad * 8];
#pragma unroll
    for (int dt = 0; dt < 4; ++dt) {
      const __bf16* vr = &Vt[dt * 16 + lq][quad * 8];
      o[dt] = MFMA(pa0, *(const bf16x8*)vr, o[dt]);
      o[dt] = MFMA(pa1, *(const bf16x8*)(vr + 32), o[dt]);
    }
  }
#pragma unroll
  for (int r = 0; r < 4; ++r) {
    float inv = 1.0f / lrun[r];
    const size_t orow =
        (rowbase + i0 + wave * 16 + quad * 4 + r) * DIM + head * DH;
#pragma unroll
    for (int dt = 0; dt < 4; ++dt)
      ho[orow + dt * 16 + lq] = (__bf16)(o[dt][r] * inv);
  }
}

// ---------------------------------------------------------------------------
extern "C" void kernel_launch(void* const* d_in, const int* in_sizes, int n_in,
                              void* d_out, int out_size, void* d_ws,
                              size_t ws_size, hipStream_t stream) {
  const float* x     = (const float*)d_in[0];  // [4096][1024]
  const float* w_q   = (const float*)d_in[1];  // [1024][1024]
  const float* w_vk  = (const float*)d_in[2];  // [1024][2048] (k cols, then v)
  const float* w_out = (const float*)d_in[3];  // [1024][1024]
  float* out = (float*)d_out;

  char* w = (char*)d_ws;  // 64 MB total
  __bf16* wqTh   = (__bf16*)(w);
  __bf16* wqTl   = (__bf16*)(w + (2ull << 20));
  __bf16* wvkTh  = (__bf16*)(w + (4ull << 20));
  __bf16* wvkTl  = (__bf16*)(w + (8ull << 20));
  __bf16* woutTh = (__bf16*)(w + (12ull << 20));
  __bf16* woutTl = (__bf16*)(w + (14ull << 20));
  __bf16* qhb    = (__bf16*)(w + (16ull << 20));
  __bf16* qlb    = (__bf16*)(w + (24ull << 20));
  __bf16* khb    = (__bf16*)(w + (32ull << 20));
  __bf16* klb    = (__bf16*)(w + (40ull << 20));
  __bf16* vTb    = (__bf16*)(w + (48ull << 20));
  __bf16* hob    = (__bf16*)(w + (56ull << 20));

  dim3 blk(256);
  transpose_split<<<dim3(16, 16), blk, 0, stream>>>(w_q, wqTh, wqTl, 1024, 1024);
  transpose_split<<<dim3(32, 16), blk, 0, stream>>>(w_vk, wvkTh, wvkTl, 2048, 1024);
  transpose_split<<<dim3(16, 16), blk, 0, stream>>>(w_out, woutTh, woutTl, 1024, 1024);

  // q = 8 * x@w_q (split3), k = x@w_k (split3)
  gemm_split3<<<dim3(8, 32), blk, 0, stream>>>(x, wqTh, wqTl, qhb, qlb, 1024, 8.0f);
  gemm_split3<<<dim3(8, 32), blk, 0, stream>>>(x, wvkTh, wvkTl, khb, klb, 1024, 1.0f);
  // v = x@w_v -> vT[b][h][d][n]
  gemm_plain<0><<<dim3(8, 32), blk, 0, stream>>>(
      x, wvkTh + (size_t)1024 * 1024, vTb, 1024);
  // attention
  attn_mfma<<<dim3(32, 32), blk, 0, stream>>>(qhb, qlb, khb, klb, vTb, hob);
  // out = ho @ w_out (f32 output)
  gemm_plain<1><<<dim3(8, 32), blk, 0, stream>>>(hob, woutTh, out, 1024);
}

// Round 3
// 281.830 us; speedup vs baseline: 4.4172x; 1.2543x over previous
//
#include <hip/hip_runtime.h>

typedef __bf16 bf16x8 __attribute__((ext_vector_type(8)));
typedef __bf16 bf16x4 __attribute__((ext_vector_type(4)));
typedef _Float16 half4 __attribute__((ext_vector_type(4)));
typedef _Float16 half8 __attribute__((ext_vector_type(8)));
typedef float f32x4 __attribute__((ext_vector_type(4)));

#define MFMA32(a, b, c) __builtin_amdgcn_mfma_f32_16x16x32_bf16(a, b, c, 0, 0, 0)
#define MFMA16(a, b, c) __builtin_amdgcn_mfma_f32_16x16x16f16(a, b, c, 0, 0, 0)

constexpr int NSEQ = 2048, DIM = 1024, DH = 64;

__device__ __forceinline__ void split_bf16(float x, __bf16& h, __bf16& l) {
  h = (__bf16)x;
  l = (__bf16)(x - (float)h);
}

// ---------------------------------------------------------------------------
// W[K=1024][N] f32 -> DH[n][k] bf16 hi (+ DL lo if n0 < lo_limit).
// ---------------------------------------------------------------------------
__global__ __launch_bounds__(256) void transpose_split(
    const float* __restrict__ W, __bf16* __restrict__ DHp,
    __bf16* __restrict__ DLp, int N, int lo_limit) {
  __shared__ float T[64][65];
  const int t = threadIdx.x;
  const int n0 = blockIdx.x * 64, k0 = blockIdx.y * 64;
  {
    const int r = t >> 2, c4 = (t & 3) * 16;
    const float* src = W + (size_t)(k0 + r) * N + n0 + c4;
    float4 v0 = ((const float4*)src)[0], v1 = ((const float4*)src)[1],
           v2 = ((const float4*)src)[2], v3 = ((const float4*)src)[3];
    *(float4*)&T[r][c4 + 0] = v0;  *(float4*)&T[r][c4 + 4] = v1;
    *(float4*)&T[r][c4 + 8] = v2;  *(float4*)&T[r][c4 + 12] = v3;
  }
  __syncthreads();
  const int rn = t >> 2, kc = (t & 3) * 16;
  bf16x8 hv[2], lv[2];
#pragma unroll
  for (int half = 0; half < 2; ++half)
#pragma unroll
    for (int j = 0; j < 8; ++j) {
      float x = T[kc + half * 8 + j][rn];
      __bf16 h, l;
      split_bf16(x, h, l);
      hv[half][j] = h;
      lv[half][j] = l;
    }
  __bf16* dh = DHp + (size_t)(n0 + rn) * 1024 + k0 + kc;
  *(bf16x8*)dh = hv[0]; *(bf16x8*)(dh + 8) = hv[1];
  if (DLp != nullptr && n0 < lo_limit) {
    __bf16* dl = DLp + (size_t)(n0 + rn) * 1024 + k0 + kc;
    *(bf16x8*)dl = lv[0]; *(bf16x8*)(dl + 8) = lv[1];
  }
}

// ---------------------------------------------------------------------------
// Fused q/k/v projection. WTh [3072][1024] bf16 (q^T | k^T | v^T),
// WTl [2048][1024] (q,k lo). kind = bn>>10: 0 -> qh/ql (scale 8, split),
// 1 -> kh/kl (split), 2 -> vT f16 [b][h][d][n].
// ---------------------------------------------------------------------------
__global__ __launch_bounds__(256, 2) void proj_fused(
    const float* __restrict__ X, const __bf16* __restrict__ WTh,
    const __bf16* __restrict__ WTl, __bf16* __restrict__ QH,
    __bf16* __restrict__ QL, __bf16* __restrict__ KHp,
    __bf16* __restrict__ KLp, _Float16* __restrict__ VT) {
  constexpr int K = 1024, GP = 40;
  __shared__ __bf16 Ash[128][GP], Asl[128][GP], Bsh[128][GP], Bsl[128][GP];
  const int t = threadIdx.x;
  const int lane = t & 63, wave = t >> 6, quad = lane >> 4, lq = lane & 15;
  const int bn = blockIdx.x * 128, bm = blockIdx.y * 128;
  const int kind = bn >> 10;  // block-uniform
  const int wm = (wave >> 1) * 64, wn = (wave & 1) * 64;
  const int am = t >> 1, ak = (t & 1) * 16;

  const float* Ag = X + (size_t)(bm + am) * K + ak;
  const __bf16* Bgh = WTh + (size_t)(bn + am) * K + ak;
  const __bf16* Bgl = WTl + (size_t)(bn + am) * K + ak;

  f32x4 acc[4][4];
#pragma unroll
  for (int i = 0; i < 4; ++i)
#pragma unroll
    for (int j = 0; j < 4; ++j) acc[i][j] = (f32x4){0.f, 0.f, 0.f, 0.f};

  float4 ar[4]; bf16x8 brh[2], brl[2];
  ar[0] = ((const float4*)Ag)[0]; ar[1] = ((const float4*)Ag)[1];
  ar[2] = ((const float4*)Ag)[2]; ar[3] = ((const float4*)Ag)[3];
  brh[0] = ((const bf16x8*)Bgh)[0]; brh[1] = ((const bf16x8*)Bgh)[1];
  if (kind < 2) { brl[0] = ((const bf16x8*)Bgl)[0]; brl[1] = ((const bf16x8*)Bgl)[1]; }

  for (int k0 = 0; k0 < K; k0 += 32) {
    __syncthreads();
    {
      const float* af = (const float*)ar;
      bf16x8 h0, h1, l0, l1;
#pragma unroll
      for (int j = 0; j < 8; ++j) { __bf16 h, l; split_bf16(af[j], h, l); h0[j] = h; l0[j] = l; }
#pragma unroll
      for (int j = 0; j < 8; ++j) { __bf16 h, l; split_bf16(af[8 + j], h, l); h1[j] = h; l1[j] = l; }
      *(bf16x8*)&Ash[am][ak] = h0; *(bf16x8*)&Ash[am][ak + 8] = h1;
      *(bf16x8*)&Bsh[am][ak] = brh[0]; *(bf16x8*)&Bsh[am][ak + 8] = brh[1];
      if (kind < 2) {
        *(bf16x8*)&Asl[am][ak] = l0; *(bf16x8*)&Asl[am][ak + 8] = l1;
        *(bf16x8*)&Bsl[am][ak] = brl[0]; *(bf16x8*)&Bsl[am][ak + 8] = brl[1];
      }
    }
    __syncthreads();
    if (k0 + 32 < K) {
      const float* A2 = Ag + k0 + 32;
      ar[0] = ((const float4*)A2)[0]; ar[1] = ((const float4*)A2)[1];
      ar[2] = ((const float4*)A2)[2]; ar[3] = ((const float4*)A2)[3];
      const __bf16* B2h = Bgh + k0 + 32;
      brh[0] = ((const bf16x8*)B2h)[0]; brh[1] = ((const bf16x8*)B2h)[1];
      if (kind < 2) {
        const __bf16* B2l = Bgl + k0 + 32;
        brl[0] = ((const bf16x8*)B2l)[0]; brl[1] = ((const bf16x8*)B2l)[1];
      }
    }
    bf16x8 ah[4], al[4];
#pragma unroll
    for (int i = 0; i < 4; ++i) ah[i] = *(const bf16x8*)&Ash[wm + i * 16 + lq][quad * 8];
    if (kind < 2) {
#pragma unroll
      for (int i = 0; i < 4; ++i) al[i] = *(const bf16x8*)&Asl[wm + i * 16 + lq][quad * 8];
#pragma unroll
      for (int j = 0; j < 4; ++j) {
        bf16x8 bh = *(const bf16x8*)&Bsh[wn + j * 16 + lq][quad * 8];
        bf16x8 bl = *(const bf16x8*)&Bsl[wn + j * 16 + lq][quad * 8];
#pragma unroll
        for (int i = 0; i < 4; ++i) {
          acc[i][j] = MFMA32(ah[i], bh, acc[i][j]);
          acc[i][j] = MFMA32(al[i], bh, acc[i][j]);
          acc[i][j] = MFMA32(ah[i], bl, acc[i][j]);
        }
      }
    } else {
#pragma unroll
      for (int j = 0; j < 4; ++j) {
        bf16x8 bh = *(const bf16x8*)&Bsh[wn + j * 16 + lq][quad * 8];
#pragma unroll
        for (int i = 0; i < 4; ++i) acc[i][j] = MFMA32(ah[i], bh, acc[i][j]);
      }
    }
  }

  if (kind == 2) {  // v -> vT[b][h][d][n] f16, 4 tokens per 8B store
#pragma unroll
    for (int i = 0; i < 4; ++i)
#pragma unroll
      for (int j = 0; j < 4; ++j) {
        const int c = (bn - 2048) + wn + j * 16 + lq;       // h*64 + d
        const int row0 = bm + wm + i * 16 + quad * 4;       // token
        const int b = row0 >> 11, n = row0 & 2047;
        const int h = c >> 6, d = c & 63;
        half4 o;
#pragma unroll
        for (int r = 0; r < 4; ++r) o[r] = (_Float16)acc[i][j][r];
        *(half4*)(VT + ((size_t)(b * 16 + h) * 64 + d) * 2048 + n) = o;
      }
  } else {
    __bf16* Dh = (kind == 0) ? QH : KHp;
    __bf16* Dl = (kind == 0) ? QL : KLp;
    const float scale = (kind == 0) ? 8.0f : 1.0f;
#pragma unroll
    for (int i = 0; i < 4; ++i)
#pragma unroll
      for (int j = 0; j < 4; ++j) {
        const int col = (bn & 1023) + wn + j * 16 + lq;
#pragma unroll
        for (int r = 0; r < 4; ++r) {
          const int row = bm + wm + i * 16 + quad * 4 + r;
          float y = acc[i][j][r] * scale;
          __bf16 h, l;
          split_bf16(y, h, l);
          Dh[(size_t)row * 1024 + col] = h;
          Dl[(size_t)row * 1024 + col] = l;
        }
      }
  }
}

// ---------------------------------------------------------------------------
// Flash attention, S^T scheme. Block = (b, h, 128 q-rows); 4 waves x 32 rows.
// S^T = K·Q^T (bf16 split-3, K=32 MFMA) -> softmax in registers (P^T lands in
// C-layout == B-layout of 16x16x16 f16 MFMA) -> O^T = V^T·P^T (no P round
// trip). O^T transposed once via LDS at the end.
// ---------------------------------------------------------------------------
__global__ __launch_bounds__(256, 2) void attn2(
    const __bf16* __restrict__ qh, const __bf16* __restrict__ ql,
    const __bf16* __restrict__ kh, const __bf16* __restrict__ kl,
    const _Float16* __restrict__ vT, __bf16* __restrict__ ho) {
  constexpr int QP = 72;  // pitch: 144 B rows, 16B-aligned, 2-way conflicts only
  __shared__ __align__(16) char smem[3 * 64 * QP * 2];
  __bf16 (*Kh)[QP] = (__bf16(*)[QP])smem;
  __bf16 (*Kl)[QP] = (__bf16(*)[QP])(smem + 64 * QP * 2);
  _Float16 (*Vt)[QP] = (_Float16(*)[QP])(smem + 2 * 64 * QP * 2);
  __bf16 (*Ot)[QP] = (__bf16(*)[QP])smem;  // epilogue reuse (128*72*2 = Kh+Kl)

  const int t = threadIdx.x;
  const int lane = t & 63, wave = t >> 6, quad = lane >> 4, lq = lane & 15;
  const int i0 = blockIdx.x * 128;
  const int bh = blockIdx.y;
  const int b = bh >> 4, head = bh & 15;
  const size_t rowbase = (size_t)b * NSEQ;

  // Q fragments (B-operand layout): lane holds Q[qrow=..+lq][dh=quad*8+j(+32)]
  bf16x8 qfh[2][2], qfl[2][2];
#pragma unroll
  for (int qt = 0; qt < 2; ++qt) {
    const size_t base =
        (rowbase + i0 + wave * 32 + qt * 16 + lq) * DIM + head * DH + quad * 8;
    qfh[qt][0] = *(const bf16x8*)(qh + base);
    qfh[qt][1] = *(const bf16x8*)(qh + base + 32);
    qfl[qt][0] = *(const bf16x8*)(ql + base);
    qfl[qt][1] = *(const bf16x8*)(ql + base + 32);
  }

  f32x4 o[2][4];
#pragma unroll
  for (int qt = 0; qt < 2; ++qt)
#pragma unroll
    for (int dt = 0; dt < 4; ++dt) o[qt][dt] = (f32x4){0.f, 0.f, 0.f, 0.f};
  float mrun[2] = {-3.0e38f, -3.0e38f};
  float lrun[2] = {0.f, 0.f};

  const int srow = t >> 2, spart = (t & 3) * 16;
  bf16x8 rk0, rk1, rl0, rl1; half8 rv0, rv1;
  auto preload = [&](int j0n) {
    const __bf16* a = kh + (rowbase + j0n + srow) * DIM + head * DH + spart;
    rk0 = ((const bf16x8*)a)[0]; rk1 = ((const bf16x8*)a)[1];
    const __bf16* c = kl + (rowbase + j0n + srow) * DIM + head * DH + spart;
    rl0 = ((const bf16x8*)c)[0]; rl1 = ((const bf16x8*)c)[1];
    const _Float16* v = vT + ((size_t)bh * 64 + srow) * NSEQ + j0n + spart;
    rv0 = ((const half8*)v)[0]; rv1 = ((const half8*)v)[1];
  };
  preload(0);

  for (int j0 = 0; j0 < NSEQ; j0 += 64) {
    __syncthreads();
    *(bf16x8*)&Kh[srow][spart] = rk0; *(bf16x8*)&Kh[srow][spart + 8] = rk1;
    *(bf16x8*)&Kl[srow][spart] = rl0; *(bf16x8*)&Kl[srow][spart + 8] = rl1;
    *(half8*)&Vt[srow][spart] = rv0;  *(half8*)&Vt[srow][spart + 8] = rv1;
    __syncthreads();
    if (j0 + 64 < NSEQ) preload(j0 + 64);

    // S^T tiles: A = K-frag (m=key), B = Q-frag; 3-product split
    f32x4 s[2][4];
#pragma unroll
    for (int nt = 0; nt < 4; ++nt) {
      const bf16x8 k0f = *(const bf16x8*)&Kh[nt * 16 + lq][quad * 8];
      const bf16x8 k1f = *(const bf16x8*)&Kh[nt * 16 + lq][quad * 8 + 32];
      const bf16x8 l0f = *(const bf16x8*)&Kl[nt * 16 + lq][quad * 8];
      const bf16x8 l1f = *(const bf16x8*)&Kl[nt * 16 + lq][quad * 8 + 32];
#pragma unroll
      for (int qt = 0; qt < 2; ++qt) {
        f32x4 sv = (f32x4){0.f, 0.f, 0.f, 0.f};
        sv = MFMA32(k0f, qfh[qt][0], sv);
        sv = MFMA32(k1f, qfh[qt][1], sv);
        sv = MFMA32(k0f, qfl[qt][0], sv);
        sv = MFMA32(k1f, qfl[qt][1], sv);
        sv = MFMA32(l0f, qfh[qt][0], sv);
        sv = MFMA32(l1f, qfh[qt][1], sv);
        s[qt][nt] = sv;
      }
    }

    // online softmax: rows are lane-resident (col=qrow=lq); keys live in
    // 4 regs x 4 quads -> local max + 2 shuffles
    half4 pb[2][4];
#pragma unroll
    for (int qt = 0; qt < 2; ++qt) {
      float mx = s[qt][0][0];
#pragma unroll
      for (int nt = 0; nt < 4; ++nt)
#pragma unroll
        for (int r = 0; r < 4; ++r) mx = fmaxf(mx, s[qt][nt][r]);
      mx = fmaxf(mx, __shfl_xor(mx, 16));
      mx = fmaxf(mx, __shfl_xor(mx, 32));
      const float mn = fmaxf(mrun[qt], mx);
      const float alpha = __expf(mrun[qt] - mn);
      mrun[qt] = mn;
      float rs = 0.f;
#pragma unroll
      for (int nt = 0; nt < 4; ++nt)
#pragma unroll
        for (int r = 0; r < 4; ++r) {
          float p = __expf(s[qt][nt][r] - mn);
          rs += p;
          pb[qt][nt][r] = (_Float16)p;
        }
      rs += __shfl_xor(rs, 16);
      rs += __shfl_xor(rs, 32);
      lrun[qt] = lrun[qt] * alpha + rs;
#pragma unroll
      for (int dt = 0; dt < 4; ++dt) o[qt][dt] *= alpha;
    }

    // O^T += V^T · P^T : A = V^T frag (m=d, k=key), B = P^T (in regs!)
#pragma unroll
    for (int dt = 0; dt < 4; ++dt) {
#pragma unroll
      for (int nt = 0; nt < 4; ++nt) {
        const half4 va = *(const half4*)&Vt[dt * 16 + lq][nt * 16 + quad * 4];
        o[0][dt] = MFMA16(va, pb[0][nt], o[0][dt]);
        o[1][dt] = MFMA16(va, pb[1][nt], o[1][dt]);
      }
    }
  }

  // epilogue: O^T (C-layout) -> LDS transpose -> coalesced bf16 store
  const float inv0 = 1.0f / lrun[0], inv1 = 1.0f / lrun[1];
  __syncthreads();  // all waves done with Kh/Kl/Vt reads
#pragma unroll
  for (int qt = 0; qt < 2; ++qt) {
    const float inv = qt ? inv1 : inv0;
#pragma unroll
    for (int dt = 0; dt < 4; ++dt)
#pragma unroll
      for (int r = 0; r < 4; ++r)
        Ot[wave * 32 + qt * 16 + lq][dt * 16 + quad * 4 + r] =
            (__bf16)(o[qt][dt][r] * inv);
  }
  __syncthreads();
  {
    const int row = t >> 1, half = t & 1;
    const __bf16* src = &Ot[row][half * 32];
    bf16x8 o0 = ((const bf16x8*)src)[0], o1 = ((const bf16x8*)src)[1],
           o2 = ((const bf16x8*)src)[2], o3 = ((const bf16x8*)src)[3];
    __bf16* dst = ho + (rowbase + i0 + row) * DIM + head * DH + half * 32;
    ((bf16x8*)dst)[0] = o0; ((bf16x8*)dst)[1] = o1;
    ((bf16x8*)dst)[2] = o2; ((bf16x8*)dst)[3] = o3;
  }
}

// ---------------------------------------------------------------------------
// out = ho(bf16) @ w_out  (hi-only bf16 MFMA, f32 out)
// ---------------------------------------------------------------------------
__global__ __launch_bounds__(256, 2) void gemm_out(
    const __bf16* __restrict__ A, const __bf16* __restrict__ BTh,
    float* __restrict__ C) {
  constexpr int K = 1024, N = 1024, GP = 40;
  __shared__ __bf16 Ash[128][GP], Bsh[128][GP];
  const int t = threadIdx.x;
  const int lane = t & 63, wave = t >> 6, quad = lane >> 4, lq = lane & 15;
  const int bm = blockIdx.y * 128, bn = blockIdx.x * 128;
  const int wm = (wave >> 1) * 64, wn = (wave & 1) * 64;
  const int am = t >> 1, ak = (t & 1) * 16;

  const __bf16* Ag = A + (size_t)(bm + am) * K + ak;
  const __bf16* Bg = BTh + (size_t)(bn + am) * K + ak;

  f32x4 acc[4][4];
#pragma unroll
  for (int i = 0; i < 4; ++i)
#pragma unroll
    for (int j = 0; j < 4; ++j) acc[i][j] = (f32x4){0.f, 0.f, 0.f, 0.f};

  bf16x8 arb[2], br[2];
  arb[0] = ((const bf16x8*)Ag)[0]; arb[1] = ((const bf16x8*)Ag)[1];
  br[0] = ((const bf16x8*)Bg)[0];  br[1] = ((const bf16x8*)Bg)[1];

  for (int k0 = 0; k0 < K; k0 += 32) {
    __syncthreads();
    *(bf16x8*)&Ash[am][ak] = arb[0]; *(bf16x8*)&Ash[am][ak + 8] = arb[1];
    *(bf16x8*)&Bsh[am][ak] = br[0];  *(bf16x8*)&Bsh[am][ak + 8] = br[1];
    __syncthreads();
    if (k0 + 32 < K) {
      const __bf16* A2 = Ag + k0 + 32;
      arb[0] = ((const bf16x8*)A2)[0]; arb[1] = ((const bf16x8*)A2)[1];
      const __bf16* B2 = Bg + k0 + 32;
      br[0] = ((const bf16x8*)B2)[0]; br[1] = ((const bf16x8*)B2)[1];
    }
    bf16x8 ah[4];
#pragma unroll
    for (int i = 0; i < 4; ++i) ah[i] = *(const bf16x8*)&Ash[wm + i * 16 + lq][quad * 8];
#pragma unroll
    for (int j = 0; j < 4; ++j) {
      bf16x8 bh = *(const bf16x8*)&Bsh[wn + j * 16 + lq][quad * 8];
#pragma unroll
      for (int i = 0; i < 4; ++i) acc[i][j] = MFMA32(ah[i], bh, acc[i][j]);
    }
  }
#pragma unroll
  for (int i = 0; i < 4; ++i)
#pragma unroll
    for (int j = 0; j < 4; ++j) {
      const int col = bn + wn + j * 16 + lq;
#pragma unroll
      for (int r = 0; r < 4; ++r) {
        const int row = bm + wm + i * 16 + quad * 4 + r;
        C[(size_t)row * N + col] = acc[i][j][r];
      }
    }
}

// ---------------------------------------------------------------------------
extern "C" void kernel_launch(void* const* d_in, const int* in_sizes, int n_in,
                              void* d_out, int out_size, void* d_ws,
                              size_t ws_size, hipStream_t stream) {
  const float* x     = (const float*)d_in[0];  // [4096][1024]
  const float* w_q   = (const float*)d_in[1];  // [1024][1024]
  const float* w_vk  = (const float*)d_in[2];  // [1024][2048] (k | v)
  const float* w_out = (const float*)d_in[3];  // [1024][1024]
  float* out = (float*)d_out;

  char* w = (char*)d_ws;  // 60 MB used
  __bf16*   wTh    = (__bf16*)(w);                 // [3072][1024]  6 MB
  __bf16*   wTl    = (__bf16*)(w + (6ull << 20));  // [2048][1024]  4 MB
  __bf16*   woutTh = (__bf16*)(w + (10ull << 20)); // [1024][1024]  2 MB
  __bf16*   qhb    = (__bf16*)(w + (12ull << 20));
  __bf16*   qlb    = (__bf16*)(w + (20ull << 20));
  __bf16*   khb    = (__bf16*)(w + (28ull << 20));
  __bf16*   klb    = (__bf16*)(w + (36ull << 20));
  _Float16* vTb    = (_Float16*)(w + (44ull << 20));
  __bf16*   hob    = (__bf16*)(w + (52ull << 20));

  dim3 blk(256);
  transpose_split<<<dim3(16, 16), blk, 0, stream>>>(w_q, wTh, wTl, 1024, 1024);
  transpose_split<<<dim3(32, 16), blk, 0, stream>>>(
      w_vk, wTh + (1ull << 20), wTl + (1ull << 20), 2048, 1024);
  transpose_split<<<dim3(16, 16), blk, 0, stream>>>(w_out, woutTh, nullptr, 1024, 0);

  proj_fused<<<dim3(24, 32), blk, 0, stream>>>(
      x, wTh, wTl, qhb, qlb, khb, klb, vTb);
  attn2<<<dim3(16, 32), blk, 0, stream>>>(qhb, qlb, khb, klb, vTb, hob);
  gemm_out<<<dim3(8, 32), blk, 0, stream>>>(hob, woutTh, out);
}

// Round 4
// 255.551 us; speedup vs baseline: 4.8714x; 1.1028x over previous
//
#include <hip/hip_runtime.h>

typedef __bf16 bf16x8 __attribute__((ext_vector_type(8)));
typedef _Float16 half4 __attribute__((ext_vector_type(4)));
typedef _Float16 half8 __attribute__((ext_vector_type(8)));
typedef float f32x4 __attribute__((ext_vector_type(4)));

#define MFMA_BF16(a, b, c) __builtin_amdgcn_mfma_f32_16x16x32_bf16(a, b, c, 0, 0, 0)
#define MFMA_F16K32(a, b, c) __builtin_amdgcn_mfma_f32_16x16x32_f16(a, b, c, 0, 0, 0)
#define MFMA_F16K16(a, b, c) __builtin_amdgcn_mfma_f32_16x16x16f16(a, b, c, 0, 0, 0)
#define EXP2F(x) __builtin_amdgcn_exp2f(x)

constexpr int NSEQ = 2048, DIM = 1024, DH = 64;
constexpr float QSCALE = 11.5415603271f;  // 8 * log2(e): logits in log2 units

__device__ __forceinline__ void split_bf16(float x, __bf16& h, __bf16& l) {
  h = (__bf16)x;
  l = (__bf16)(x - (float)h);
}

// async 16B/lane global->LDS. lds base must be wave-uniform; lane i's 16B
// lands at lds + i*16.
__device__ __forceinline__ void ld_lds16(void* lds, const void* g) {
  __builtin_amdgcn_global_load_lds(
      (const __attribute__((address_space(1))) void*)g,
      (__attribute__((address_space(3))) void*)lds, 16, 0, 0);
}

// ---------------------------------------------------------------------------
// Weight prep: transpose 64x64 f32 tiles.
// bx 0..15: w_q   -> WTh/WTl rows 0..1023, scaled by QSCALE (bf16 h/l)
// bx 16..47: w_vk -> rows 1024..3071 (k then v) (bf16 h/l)
// bx 48..63: w_out-> WoT fp16 [n][k]
// ---------------------------------------------------------------------------
__global__ __launch_bounds__(256) void prep_w(
    const float* __restrict__ w_q, const float* __restrict__ w_vk,
    const float* __restrict__ w_out, __bf16* __restrict__ WTh,
    __bf16* __restrict__ WTl, _Float16* __restrict__ WoT) {
  __shared__ float T[64][65];
  const int t = threadIdx.x;
  const int bx = blockIdx.x, k0 = blockIdx.y * 64;
  const float* src;
  int srcN, n0, dstrow, mode;
  float scale;
  if (bx < 16) {
    src = w_q; srcN = 1024; n0 = bx * 64; dstrow = n0; scale = QSCALE; mode = 0;
  } else if (bx < 48) {
    src = w_vk; srcN = 2048; n0 = (bx - 16) * 64; dstrow = 1024 + n0;
    scale = 1.0f; mode = 0;
  } else {
    src = w_out; srcN = 1024; n0 = (bx - 48) * 64; dstrow = n0;
    scale = 1.0f; mode = 1;
  }
  {
    const int r = t >> 2, c4 = (t & 3) * 16;
    const float* s = src + (size_t)(k0 + r) * srcN + n0 + c4;
    float4 v0 = ((const float4*)s)[0], v1 = ((const float4*)s)[1],
           v2 = ((const float4*)s)[2], v3 = ((const float4*)s)[3];
    *(float4*)&T[r][c4 + 0] = v0;  *(float4*)&T[r][c4 + 4] = v1;
    *(float4*)&T[r][c4 + 8] = v2;  *(float4*)&T[r][c4 + 12] = v3;
  }
  __syncthreads();
  const int rn = t >> 2, kc = (t & 3) * 16;
  if (mode == 0) {
    bf16x8 hv[2], lv[2];
#pragma unroll
    for (int half = 0; half < 2; ++half)
#pragma unroll
      for (int j = 0; j < 8; ++j) {
        float x = T[kc + half * 8 + j][rn] * scale;
        __bf16 h, l;
        split_bf16(x, h, l);
        hv[half][j] = h; lv[half][j] = l;
      }
    __bf16* dh = WTh + (size_t)(dstrow + rn) * 1024 + k0 + kc;
    __bf16* dl = WTl + (size_t)(dstrow + rn) * 1024 + k0 + kc;
    *(bf16x8*)dh = hv[0]; *(bf16x8*)(dh + 8) = hv[1];
    *(bf16x8*)dl = lv[0]; *(bf16x8*)(dl + 8) = lv[1];
  } else {
    half8 hv[2];
#pragma unroll
    for (int half = 0; half < 2; ++half)
#pragma unroll
      for (int j = 0; j < 8; ++j)
        hv[half][j] = (_Float16)T[kc + half * 8 + j][rn];
    _Float16* d = WoT + (size_t)(n0 + rn) * 1024 + k0 + kc;
    *(half8*)d = hv[0]; *(half8*)(d + 8) = hv[1];
  }
}

// ---------------------------------------------------------------------------
// Fused q/k/v projection, async-staged + swizzled LDS.
// A = x (f32, staged raw, split to bf16 h/l at frag read).
// kind 0: q -> QH/QL (weights pre-scaled); 1: k -> KH/KL; 2: v -> VT fp16.
// q/k: 3-product split; v: 2-product (x-lo correction).
// ---------------------------------------------------------------------------
__global__ __launch_bounds__(256, 3) void proj3(
    const float* __restrict__ X, const __bf16* __restrict__ WTh,
    const __bf16* __restrict__ WTl, __bf16* __restrict__ QH,
    __bf16* __restrict__ QL, __bf16* __restrict__ KH,
    __bf16* __restrict__ KL, _Float16* __restrict__ VT) {
  __shared__ __align__(16) float Axs[128 * 32];     // f32, chunk c^=(r&7)
  __shared__ __align__(16) __bf16 Bhs[128 * 32];    // bf16, pair-row swizzle
  __shared__ __align__(16) __bf16 Bls[128 * 32];
  const int t = threadIdx.x;
  const int lane = t & 63, wave = t >> 6, quad = lane >> 4, lq = lane & 15;
  const int bn = blockIdx.x * 128, bm = blockIdx.y * 128;
  const int kind = bn >> 10;
  const int wm = (wave >> 1) * 64, wn = (wave & 1) * 64;

  // A staging (f32 rows = 128B = 8 chunks): issue = 8 rows; wave: 4 issues.
  const int arow = wave * 32 + (lane >> 3);
  const int achk = (lane & 7) ^ (lane >> 3);       // (r&7) == lane>>3
  const float* ag = X + (size_t)(bm + arow) * DIM + achk * 4;
  // B staging (bf16 rows = 64B; pair-row 128B units): issue = 16 rows; 2/wave.
  const int bco = (lane & 7) ^ (lane >> 3);        // unit chunk (u&7==lane>>3)
  const int brow = 2 * (lane >> 3) + (bco >> 2);
  const int bcc = bco & 3;
  const __bf16* bgh = WTh + (size_t)(bn + wave * 32 + brow) * DIM + bcc * 8;
  const __bf16* bgl = WTl + (size_t)(bn + wave * 32 + brow) * DIM + bcc * 8;

  // read-side swizzle constants (element offsets)
  const int swzA0 = ((2 * quad) ^ (lq & 7)) * 4;
  const int swzA1 = ((2 * quad + 1) ^ (lq & 7)) * 4;
  const int swzB = ((((lq & 1) << 2) | quad) ^ ((lq >> 1) & 7)) * 8;

  f32x4 acc[4][4];
#pragma unroll
  for (int i = 0; i < 4; ++i)
#pragma unroll
    for (int j = 0; j < 4; ++j) acc[i][j] = (f32x4){0.f, 0.f, 0.f, 0.f};

  for (int k0 = 0; k0 < DIM; k0 += 32) {
#pragma unroll
    for (int q = 0; q < 4; ++q)
      ld_lds16(Axs + (wave * 32 + q * 8) * 32, ag + (size_t)q * 8 * DIM);
#pragma unroll
    for (int q = 0; q < 2; ++q) {
      ld_lds16(Bhs + (wave * 32 + q * 16) * 32, bgh + (size_t)q * 16 * DIM);
      if (kind < 2)
        ld_lds16(Bls + (wave * 32 + q * 16) * 32, bgl + (size_t)q * 16 * DIM);
    }
    ag += 32; bgh += 32; bgl += 32;
    __syncthreads();   // drain DMA; tile ready

    bf16x8 ah[4], al[4];
#pragma unroll
    for (int i = 0; i < 4; ++i) {
      const int off = (wm + i * 16 + lq) * 32;
      float4 a0 = *(const float4*)&Axs[off + swzA0];
      float4 a1 = *(const float4*)&Axs[off + swzA1];
      float av[8] = {a0.x, a0.y, a0.z, a0.w, a1.x, a1.y, a1.z, a1.w};
#pragma unroll
      for (int e = 0; e < 8; ++e) {
        __bf16 h, l;
        split_bf16(av[e], h, l);
        ah[i][e] = h; al[i][e] = l;
      }
    }
#pragma unroll
    for (int j = 0; j < 4; ++j) {
      const int row = wn + j * 16 + lq;
      const int boff = (row >> 1) * 64 + swzB;
      bf16x8 bh = *(const bf16x8*)&Bhs[boff];
      if (kind < 2) {
        bf16x8 bl = *(const bf16x8*)&Bls[boff];
#pragma unroll
        for (int i = 0; i < 4; ++i) {
          acc[i][j] = MFMA_BF16(ah[i], bh, acc[i][j]);
          acc[i][j] = MFMA_BF16(al[i], bh, acc[i][j]);
          acc[i][j] = MFMA_BF16(ah[i], bl, acc[i][j]);
        }
      } else {
#pragma unroll
        for (int i = 0; i < 4; ++i) {
          acc[i][j] = MFMA_BF16(ah[i], bh, acc[i][j]);
          acc[i][j] = MFMA_BF16(al[i], bh, acc[i][j]);
        }
      }
    }
    __syncthreads();   // all waves done reading before next DMA overwrites
  }

  if (kind == 2) {  // v -> vT[b][h][d][n] fp16, 4 consecutive tokens / store
#pragma unroll
    for (int i = 0; i < 4; ++i)
#pragma unroll
      for (int j = 0; j < 4; ++j) {
        const int c = (bn - 2048) + wn + j * 16 + lq;  // h*64 + d
        const int row0 = bm + wm + i * 16 + quad * 4;  // token
        const int b = row0 >> 11, n = row0 & 2047;
        const int h = c >> 6, d = c & 63;
        half4 o;
#pragma unroll
        for (int r = 0; r < 4; ++r) o[r] = (_Float16)acc[i][j][r];
        *(half4*)(VT + ((size_t)(b * 16 + h) * 64 + d) * 2048 + n) = o;
      }
  } else {
    __bf16* Dh = (kind == 0) ? QH : KH;
    __bf16* Dl = (kind == 0) ? QL : KL;
#pragma unroll
    for (int i = 0; i < 4; ++i)
#pragma unroll
      for (int j = 0; j < 4; ++j) {
        const int col = (bn & 1023) + wn + j * 16 + lq;
#pragma unroll
        for (int r = 0; r < 4; ++r) {
          const int row = bm + wm + i * 16 + quad * 4 + r;
          __bf16 h, l;
          split_bf16(acc[i][j][r], h, l);
          Dh[(size_t)row * 1024 + col] = h;
          Dl[(size_t)row * 1024 + col] = l;
        }
      }
  }
}

// ---------------------------------------------------------------------------
// Flash attention: S^T = K.Q^T (bf16 3-product), softmax in regs (exp2),
// O^T = V^T.P^T (fp16, P^T straight from C-layout regs). TJ=128 keys/iter,
// async swizzled staging of Kh/Kl/Vt. ho fp16.
// ---------------------------------------------------------------------------
__global__ __launch_bounds__(256, 2) void attn3(
    const __bf16* __restrict__ qh, const __bf16* __restrict__ ql,
    const __bf16* __restrict__ kh, const __bf16* __restrict__ kl,
    const _Float16* __restrict__ vT, _Float16* __restrict__ ho) {
  __shared__ __align__(16) char smem[49152];
  __bf16* Khs = (__bf16*)smem;               // [128][64], chunk c^=(r&7)
  __bf16* Kls = (__bf16*)(smem + 16384);
  _Float16* Vts = (_Float16*)(smem + 32768); // [64][128], chunk c^=(r&15)
  _Float16* Ots = (_Float16*)smem;           // epilogue reuse [128][72]

  const int t = threadIdx.x;
  const int lane = t & 63, wave = t >> 6, quad = lane >> 4, lq = lane & 15;
  const int i0 = blockIdx.x * 128;
  const int bh = blockIdx.y, b = bh >> 4, head = bh & 15;
  const size_t rowbase = (size_t)b * NSEQ;

  // Q fragments (B-operand layout), pinned in registers
  bf16x8 qfh[2][2], qfl[2][2];
#pragma unroll
  for (int qt = 0; qt < 2; ++qt) {
    const size_t base =
        (rowbase + i0 + wave * 32 + qt * 16 + lq) * DIM + head * DH + quad * 8;
    qfh[qt][0] = *(const bf16x8*)(qh + base);
    qfh[qt][1] = *(const bf16x8*)(qh + base + 32);
    qfl[qt][0] = *(const bf16x8*)(ql + base);
    qfl[qt][1] = *(const bf16x8*)(ql + base + 32);
  }

  f32x4 o[2][4];
#pragma unroll
  for (int qt = 0; qt < 2; ++qt)
#pragma unroll
    for (int dt = 0; dt < 4; ++dt) o[qt][dt] = (f32x4){0.f, 0.f, 0.f, 0.f};
  float mrun[2] = {-3.0e38f, -3.0e38f};
  float lrun[2] = {0.f, 0.f};

  // K staging: issue = 8 rows x 128B; wave rows wave*32..+31 (4 issues)
  const int kchk = (lane & 7) ^ (lane >> 3);
  const __bf16* khg =
      kh + (rowbase + wave * 32 + (lane >> 3)) * DIM + head * DH + kchk * 8;
  const __bf16* klg =
      kl + (rowbase + wave * 32 + (lane >> 3)) * DIM + head * DH + kchk * 8;
  // V staging: issue = 4 rows x 256B; wave rows wave*16..+15 (4 issues)
  int vco[4];
#pragma unroll
  for (int is = 0; is < 4; ++is)
    vco[is] = ((lane & 15) ^ (is * 4 + (lane >> 4))) * 8;
  const _Float16* vg =
      vT + ((size_t)bh * 64 + wave * 16 + (lane >> 4)) * NSEQ;

  const int swzK0 = ((quad) ^ (lq & 7)) * 8;
  const int swzK1 = ((quad + 4) ^ (lq & 7)) * 8;

  for (int j0 = 0; j0 < NSEQ; j0 += 128) {
#pragma unroll
    for (int is = 0; is < 4; ++is) {
      ld_lds16(Khs + (wave * 32 + is * 8) * 64, khg + (size_t)is * 8 * DIM);
      ld_lds16(Kls + (wave * 32 + is * 8) * 64, klg + (size_t)is * 8 * DIM);
      ld_lds16(Vts + (wave * 16 + is * 4) * 128,
               vg + (size_t)is * 4 * NSEQ + vco[is]);
    }
    khg += (size_t)128 * DIM; klg += (size_t)128 * DIM; vg += 128;
    __syncthreads();

#pragma unroll
    for (int jh = 0; jh < 2; ++jh) {
      f32x4 s[2][4];
#pragma unroll
      for (int nt = 0; nt < 4; ++nt) {
        const int roff = (jh * 64 + nt * 16 + lq) * 64;
        bf16x8 k0f = *(const bf16x8*)&Khs[roff + swzK0];
        bf16x8 k1f = *(const bf16x8*)&Khs[roff + swzK1];
        bf16x8 l0f = *(const bf16x8*)&Kls[roff + swzK0];
        bf16x8 l1f = *(const bf16x8*)&Kls[roff + swzK1];
#pragma unroll
        for (int qt = 0; qt < 2; ++qt) {
          f32x4 sv = (f32x4){0.f, 0.f, 0.f, 0.f};
          sv = MFMA_BF16(k0f, qfh[qt][0], sv);
          sv = MFMA_BF16(k1f, qfh[qt][1], sv);
          sv = MFMA_BF16(k0f, qfl[qt][0], sv);
          sv = MFMA_BF16(k1f, qfl[qt][1], sv);
          sv = MFMA_BF16(l0f, qfh[qt][0], sv);
          sv = MFMA_BF16(l1f, qfh[qt][1], sv);
          s[qt][nt] = sv;
        }
      }
      half4 pb[2][4];
#pragma unroll
      for (int qt = 0; qt < 2; ++qt) {
        float mx = s[qt][0][0];
#pragma unroll
        for (int nt = 0; nt < 4; ++nt)
#pragma unroll
          for (int r = 0; r < 4; ++r) mx = fmaxf(mx, s[qt][nt][r]);
        mx = fmaxf(mx, __shfl_xor(mx, 16));
        mx = fmaxf(mx, __shfl_xor(mx, 32));
        const float mn = fmaxf(mrun[qt], mx);
        const float alpha = EXP2F(mrun[qt] - mn);
        mrun[qt] = mn;
        float rs = 0.f;
#pragma unroll
        for (int nt = 0; nt < 4; ++nt)
#pragma unroll
          for (int r = 0; r < 4; ++r) {
            float p = EXP2F(s[qt][nt][r] - mn);
            rs += p;
            pb[qt][nt][r] = (_Float16)p;
          }
        rs += __shfl_xor(rs, 16);
        rs += __shfl_xor(rs, 32);
        lrun[qt] = lrun[qt] * alpha + rs;
#pragma unroll
        for (int dt = 0; dt < 4; ++dt) o[qt][dt] *= alpha;
      }
#pragma unroll
      for (int dt = 0; dt < 4; ++dt) {
        const int vrow = (dt * 16 + lq) * 128;
#pragma unroll
        for (int nt = 0; nt < 4; ++nt) {
          const int ntj = jh * 4 + nt;
          const int voff =
              vrow + ((2 * ntj + (quad >> 1)) ^ lq) * 8 + (quad & 1) * 4;
          half4 va = *(const half4*)&Vts[voff];
          o[0][dt] = MFMA_F16K16(va, pb[0][nt], o[0][dt]);
          o[1][dt] = MFMA_F16K16(va, pb[1][nt], o[1][dt]);
        }
      }
    }
    __syncthreads();
  }

  // epilogue: O^T (C-layout) -> LDS transpose -> coalesced fp16 store
  const float inv0 = 1.0f / lrun[0], inv1 = 1.0f / lrun[1];
#pragma unroll
  for (int qt = 0; qt < 2; ++qt) {
    const float inv = qt ? inv1 : inv0;
#pragma unroll
    for (int dt = 0; dt < 4; ++dt)
#pragma unroll
      for (int r = 0; r < 4; ++r)
        Ots[(wave * 32 + qt * 16 + lq) * 72 + dt * 16 + quad * 4 + r] =
            (_Float16)(o[qt][dt][r] * inv);
  }
  __syncthreads();
  {
    const int row = t >> 1, hf = t & 1;
    const _Float16* src = &Ots[row * 72 + hf * 32];
    half8 o0 = ((const half8*)src)[0], o1 = ((const half8*)src)[1],
          o2 = ((const half8*)src)[2], o3 = ((const half8*)src)[3];
    _Float16* dst = ho + (rowbase + i0 + row) * DIM + head * DH + hf * 32;
    ((half8*)dst)[0] = o0; ((half8*)dst)[1] = o1;
    ((half8*)dst)[2] = o2; ((half8*)dst)[3] = o3;
  }
}

// ---------------------------------------------------------------------------
// out = ho(fp16) @ w_out (fp16 single product, f32 out). 64x128 tiles.
// ---------------------------------------------------------------------------
__global__ __launch_bounds__(256, 2) void gemm_out(
    const _Float16* __restrict__ A, const _Float16* __restrict__ BT,
    float* __restrict__ C) {
  __shared__ __align__(16) _Float16 Ahs[64 * 32], Bhs[128 * 32];
  const int t = threadIdx.x;
  const int lane = t & 63, wave = t >> 6, quad = lane >> 4, lq = lane & 15;
  const int bn = blockIdx.x * 128, bm = blockIdx.y * 64;
  const int wm = (wave >> 1) * 32, wn = (wave & 1) * 64;

  const int bco = (lane & 7) ^ (lane >> 3);
  const int brow = 2 * (lane >> 3) + (bco >> 2);
  const int bcc = bco & 3;
  const _Float16* ag = A + (size_t)(bm + wave * 16 + brow) * DIM + bcc * 8;
  const _Float16* bg = BT + (size_t)(bn + wave * 32 + brow) * DIM + bcc * 8;
  const int swzB = ((((lq & 1) << 2) | quad) ^ ((lq >> 1) & 7)) * 8;

  f32x4 acc[2][4];
#pragma unroll
  for (int i = 0; i < 2; ++i)
#pragma unroll
    for (int j = 0; j < 4; ++j) acc[i][j] = (f32x4){0.f, 0.f, 0.f, 0.f};

  for (int k0 = 0; k0 < DIM; k0 += 32) {
    ld_lds16(Ahs + (wave * 16) * 32, ag);
#pragma unroll
    for (int q = 0; q < 2; ++q)
      ld_lds16(Bhs + (wave * 32 + q * 16) * 32, bg + (size_t)q * 16 * DIM);
    ag += 32; bg += 32;
    __syncthreads();
    half8 ah[2];
#pragma unroll
    for (int i = 0; i < 2; ++i) {
      const int row = wm + i * 16 + lq;
      ah[i] = *(const half8*)&Ahs[(row >> 1) * 64 + swzB];
    }
#pragma unroll
    for (int j = 0; j < 4; ++j) {
      const int row = wn + j * 16 + lq;
      half8 bh = *(const half8*)&Bhs[(row >> 1) * 64 + swzB];
#pragma unroll
      for (int i = 0; i < 2; ++i) acc[i][j] = MFMA_F16K32(ah[i], bh, acc[i][j]);
    }
    __syncthreads();
  }
#pragma unroll
  for (int i = 0; i < 2; ++i)
#pragma unroll
    for (int j = 0; j < 4; ++j) {
      const int col = bn + wn + j * 16 + lq;
#pragma unroll
      for (int r = 0; r < 4; ++r) {
        const int row = bm + wm + i * 16 + quad * 4 + r;
        C[(size_t)row * 1024 + col] = acc[i][j][r];
      }
    }
}

// ---------------------------------------------------------------------------
extern "C" void kernel_launch(void* const* d_in, const int* in_sizes, int n_in,
                              void* d_out, int out_size, void* d_ws,
                              size_t ws_size, hipStream_t stream) {
  const float* x     = (const float*)d_in[0];
  const float* w_q   = (const float*)d_in[1];
  const float* w_vk  = (const float*)d_in[2];
  const float* w_out = (const float*)d_in[3];
  float* out = (float*)d_out;

  char* w = (char*)d_ws;  // 62 MB used
  __bf16*   wTh = (__bf16*)(w);                  // [3072][1024] 6MB
  __bf16*   wTl = (__bf16*)(w + (6ull << 20));   // [3072][1024] 6MB
  __bf16*   qhb = (__bf16*)(w + (12ull << 20));  // 8MB each
  __bf16*   qlb = (__bf16*)(w + (20ull << 20));
  __bf16*   khb = (__bf16*)(w + (28ull << 20));
  __bf16*   klb = (__bf16*)(w + (36ull << 20));
  _Float16* vTb = (_Float16*)(w + (44ull << 20)); // 8MB
  _Float16* hob = (_Float16*)(w + (52ull << 20)); // 8MB
  _Float16* woT = (_Float16*)(w + (60ull << 20)); // 2MB

  dim3 blk(256);
  prep_w<<<dim3(64, 16), blk, 0, stream>>>(w_q, w_vk, w_out, wTh, wTl, woT);
  proj3<<<dim3(24, 32), blk, 0, stream>>>(
      x, wTh, wTl, qhb, qlb, khb, klb, vTb);
  attn3<<<dim3(16, 32), blk, 0, stream>>>(qhb, qlb, khb, klb, vTb, hob);
  gemm_out<<<dim3(8, 64), blk, 0, stream>>>(hob, woT, out);
}